// Round 3
// baseline (359.321 us; speedup 1.0000x reference)
//
#include <hip/hip_runtime.h>
#include <math.h>

#define BB 8
#define CC 512
#define LL 4096
#define DQK 64

typedef short short8 __attribute__((ext_vector_type(8)));
typedef unsigned short ushort4v __attribute__((ext_vector_type(4)));
typedef unsigned short ushort8v __attribute__((ext_vector_type(8)));
typedef float floatx4 __attribute__((ext_vector_type(4)));
typedef unsigned int uint4v __attribute__((ext_vector_type(4)));

__device__ __forceinline__ unsigned short f2bf(float f) {
    union { float f; unsigned u; } v; v.f = f;
    unsigned r = v.u + 0x7fffu + ((v.u >> 16) & 1u);
    return (unsigned short)(r >> 16);
}

// async global->LDS DMA, 16B per lane. LDS dest is wave-uniform base + lane*16.
__device__ __forceinline__ void load_lds16(const void* gptr, void* lptr) {
    __builtin_amdgcn_global_load_lds(
        (const __attribute__((address_space(1))) unsigned int*)gptr,
        (__attribute__((address_space(3))) unsigned int*)lptr, 16, 0, 0);
}

__device__ __forceinline__ unsigned cvt_pk_bf16(float lo, float hi) {
    unsigned r;
    asm("v_cvt_pk_bf16_f32 %0, %1, %2" : "=v"(r) : "v"(lo), "v"(hi));
    return r;
}

// ---------------- transpose + cast: xt[b][l][c] = bf16(x[b][c][l]) ----------------
__global__ __launch_bounds__(256) void k_transpose(const float* __restrict__ x,
                                                   unsigned short* __restrict__ xt) {
    __shared__ unsigned short tile[64][72];
    int l0 = blockIdx.x * 64, c0 = blockIdx.y * 64, b = blockIdx.z;
    int t = threadIdx.x;
    int r  = t >> 2;              // c-row 0..63
    int ch = (t & 3) * 16;        // l-chunk
    const float* src = x + ((size_t)b * CC + c0 + r) * LL + l0 + ch;
#pragma unroll
    for (int j = 0; j < 4; ++j) {
        floatx4 v = *(const floatx4*)(src + j * 4);
        ushort4v u = { f2bf(v[0]), f2bf(v[1]), f2bf(v[2]), f2bf(v[3]) };
        *(ushort4v*)(&tile[r][ch + j * 4]) = u;
    }
    __syncthreads();
    int lr  = t >> 2;             // l-row 0..63
    int cch = (t & 3) * 16;       // c-chunk
    ushort8v o0, o1;
#pragma unroll
    for (int j = 0; j < 8; ++j) o0[j] = tile[cch + j][lr];
#pragma unroll
    for (int j = 0; j < 8; ++j) o1[j] = tile[cch + 8 + j][lr];
    unsigned short* dst = xt + ((size_t)b * LL + l0 + lr) * CC + c0 + cch;
    *(ushort8v*)(dst)     = o0;
    *(ushort8v*)(dst + 8) = o1;
}

// ---------------- weight cast ----------------
__global__ void k_castw(const float* __restrict__ wq, const float* __restrict__ wk,
                        const float* __restrict__ wv,
                        unsigned short* __restrict__ wqb, unsigned short* __restrict__ wkb,
                        unsigned short* __restrict__ wvb) {
    int i = blockIdx.x * 256 + threadIdx.x;   // grid covers 262144
    if (i < DQK * CC) { wqb[i] = f2bf(wq[i]); wkb[i] = f2bf(wk[i]); }
    wvb[i] = f2bf(wv[i]);
}

// ---------------- fused q/k/v projection ----------------
// One block per (64-l tile, b). xt tile (64 l x 512 c, 64 KB) staged ONCE in LDS.
// W prefetch restructured to 8-fragment half-steps (rolling wA/wB = 64 VGPR instead
// of the 128-VGPR full double-buffer) -> no spill risk, shorter dep stalls.
// z<8: V rows (out [d][l]);  z==8: Q (out [l][d], LOG2E folded);  z==9: K (out [l][d]).
__global__ __launch_bounds__(256) void k_projall(const unsigned short* __restrict__ xt,
                                                 const unsigned short* __restrict__ wqb,
                                                 const unsigned short* __restrict__ wkb,
                                                 const unsigned short* __restrict__ wvb,
                                                 const float* __restrict__ bq,
                                                 const float* __restrict__ bk,
                                                 const float* __restrict__ bv,
                                                 unsigned short* __restrict__ qout,
                                                 unsigned short* __restrict__ kout,
                                                 unsigned short* __restrict__ vout) {
    int l0 = blockIdx.x * 64;
    int b  = blockIdx.y;
    int tid = threadIdx.x;
    int w = tid >> 6, lane = tid & 63;
    int lane16 = lane & 15, g = lane >> 4;
    __shared__ unsigned short xtile[64 * 512];
    {
        const unsigned short* xg = xt + ((size_t)b * LL + l0) * CC;
        int pg = tid & 63;
#pragma unroll
        for (int ci = 0; ci < 16; ++ci) {
            int r  = ci * 4 + (tid >> 6);
            int sg = (pg & 56) | ((pg ^ r) & 7);
            load_lds16(xg + (size_t)r * CC + sg * 8, xtile + ((size_t)ci * 256 + tid) * 8);
        }
    }

    int xe = (g ^ (lane16 & 7)) * 8;
    int xo = ((g + 4) ^ (lane16 & 7)) * 8;

    // 8 W fragments for half-step hs = z*2 + kh (kk = kh*8 .. kh*8+7)
    auto loadW8 = [&](short8 (&af)[8], int hs) {
        int z = hs >> 1, kh = hs & 1;
        const unsigned short* base;
        if (z < 8)       base = wvb + (size_t)(z * 64 + w * 16 + lane16) * CC;
        else if (z == 8) base = wqb + (size_t)(w * 16 + lane16) * CC;
        else             base = wkb + (size_t)(w * 16 + lane16) * CC;
        base += g * 8 + kh * 256;          // kh*8 frags * 32 ushort stride
#pragma unroll
        for (int kk = 0; kk < 8; ++kk) af[kk] = *(const short8*)(base + kk * 32);
    };

    short8 wA[8], wB[8];
    loadW8(wA, 0);
    __syncthreads();   // xtile DMA drained

    for (int z = 0; z < 10; ++z) {
        loadW8(wB, z * 2 + 1);                 // prefetch kh=1 under kh=0 MFMAs
        floatx4 acc[4];
#pragma unroll
        for (int nt = 0; nt < 4; ++nt) acc[nt] = {0.f, 0.f, 0.f, 0.f};
#pragma unroll
        for (int nt = 0; nt < 4; ++nt)
#pragma unroll
            for (int kk = 0; kk < 8; ++kk) {
                int off = (nt * 16 + lane16) * 512 + (kk >> 1) * 64 + ((kk & 1) ? xo : xe);
                short8 bfrag = *(const short8*)(xtile + off);
                acc[nt] = __builtin_amdgcn_mfma_f32_16x16x32_bf16(wA[kk], bfrag, acc[nt], 0, 0, 0);
            }
        if (z + 1 < 10) loadW8(wA, (z + 1) * 2);   // prefetch next z kh=0 under kh=1
#pragma unroll
        for (int nt = 0; nt < 4; ++nt)
#pragma unroll
            for (int kk = 0; kk < 8; ++kk) {
                int kk8 = kk + 8;
                int off = (nt * 16 + lane16) * 512 + (kk8 >> 1) * 64 + ((kk8 & 1) ? xo : xe);
                short8 bfrag = *(const short8*)(xtile + off);
                acc[nt] = __builtin_amdgcn_mfma_f32_16x16x32_bf16(wB[kk], bfrag, acc[nt], 0, 0, 0);
            }
        // write out z's results
#pragma unroll
        for (int nt = 0; nt < 4; ++nt) {
            int l = l0 + nt * 16 + lane16;
            if (z < 8) {
#pragma unroll
                for (int r = 0; r < 4; ++r) {
                    int d = z * 64 + w * 16 + g * 4 + r;
                    vout[((size_t)b * CC + d) * LL + l] = f2bf(acc[nt][r] + bv[d]);
                }
            } else {
                const float* bias = (z == 8) ? bq : bk;
                float sc = (z == 8) ? 1.4426950408889634f : 1.0f;
                ushort4v o;
#pragma unroll
                for (int r = 0; r < 4; ++r)
                    o[r] = f2bf((acc[nt][r] + bias[w * 16 + g * 4 + r]) * sc);
                unsigned short* dst = ((z == 8) ? qout : kout)
                                      + ((size_t)b * LL + l) * DQK + w * 16 + g * 4;
                *(ushort4v*)dst = o;
            }
        }
    }
}

// ---------------- fused flash attention ----------------
// grid: (L/128, B, C/256). 4 waves x 32 q-rows.
// Round-3 change: counted-vmcnt pipeline (T3+T4) replacing the per-tile vmcnt(0)
// drain of __syncthreads:
//   top of tile t:  vmcnt(8)  -> only K(t)'s 2 DMAs drained; S runs while V(t) lands
//   then issue K(t+1)+V(t+1)  -> stay in flight across the whole tile
//   before PV:      vmcnt(10) -> V(t) drained, t+1's 10 DMAs untouched
// All in-loop vmem = exactly these 10 DMAs/tile (q before loop, x after), so the
// counts are deterministic. Raw s_barrier, no compiler drain.
__global__ __launch_bounds__(256, 2) void k_attn(const unsigned short* __restrict__ q,
                                                 const unsigned short* __restrict__ kws,
                                                 const unsigned short* __restrict__ vws,
                                                 const float* __restrict__ x,
                                                 const float* __restrict__ gamma,
                                                 float* __restrict__ out) {
    // bijective remap: group g=(b,z) of 32 blocks -> XCD g&7 (L2-fit K/V working set)
    int bid = blockIdx.x + 32 * blockIdx.y + 256 * blockIdx.z;
    int x8  = bid & 7;
    int ii  = bid >> 3;                  // 0..63
    int wg  = (x8 + 8 * (ii >> 5)) * 32 + (ii & 31);
    int i0 = (wg & 31) * 128;
    int b  = (wg >> 5) & 7;
    int c0 = (wg >> 8) * 256;

    int tid = threadIdx.x;
    int w = tid >> 6, lane = tid & 63;
    int lane16 = lane & 15, g = lane >> 4;
    int iw = i0 + w * 32;

    __shared__ unsigned short kt[2][64 * 64];    // 2 x  8 KB: K tile [j][d], swizzled
    __shared__ unsigned short vt[2][256 * 64];   // 2 x 32 KB: V tile [c][j], swizzled

    // Q fragments (B-operand of swapped QK^T: col=lane16 -> q-row i)
    short8 qf[2][2];
#pragma unroll
    for (int m = 0; m < 2; ++m) {
        const unsigned short* qrow = q + ((size_t)b * LL + iw + m * 16 + lane16) * DQK + g * 8;
        qf[m][0] = *(const short8*)(qrow);
        qf[m][1] = *(const short8*)(qrow + 32);
    }

    const unsigned short* kglob = kws + (size_t)b * LL * DQK;
    const unsigned short* vglob = vws + ((size_t)b * CC + c0) * LL;
    int gr    = (tid & 7) ^ ((tid >> 3) & 7);
    int koff0 = (tid >> 3) * DQK + gr * 8;
    int voff0 = (tid >> 3) * LL  + gr * 8;

    // fragment read offsets (ushort units) within one buffer
    int kro[2], vro[2];
#pragma unroll
    for (int kk = 0; kk < 2; ++kk) {
        int sw = (kk * 4 + g) ^ (lane16 & 7);
        kro[kk] = lane16 * 64 + sw * 8;
        vro[kk] = lane16 * 64 + sw * 8;
    }

    short8 ones;
#pragma unroll
    for (int j = 0; j < 8; ++j) ones[j] = (short)0x3f80;   // bf16 1.0

    floatx4 O[2][16];
#pragma unroll
    for (int m = 0; m < 2; ++m)
#pragma unroll
        for (int nt = 0; nt < 16; ++nt) O[m][nt] = {0.f, 0.f, 0.f, 0.f};
    floatx4 Ol[2];
#pragma unroll
    for (int m = 0; m < 2; ++m) Ol[m] = {0.f, 0.f, 0.f, 0.f};

    auto stageK = [&](int j0n, int buf) {
        const unsigned short* ks = kglob + j0n * DQK + koff0;
        unsigned short* kd = &kt[buf][tid * 8];
        load_lds16(ks,        kd);
        load_lds16(ks + 2048, kd + 2048);
    };
    auto stageV = [&](int j0n, int buf) {
        const unsigned short* vs = vglob + j0n + voff0;
        unsigned short* vd = &vt[buf][tid * 8];
#pragma unroll
        for (int i = 0; i < 8; ++i)
            load_lds16(vs + i * 131072, vd + i * 2048);
    };

    // exp + in-register repack + ones-MFMA for one 32-j half
    auto softmax_half = [&](floatx4 (&Sh)[2][2], short8 (&paD)[2]) {
#pragma unroll
        for (int m = 0; m < 2; ++m) {
            float e0[4], e1[4];
#pragma unroll
            for (int r = 0; r < 4; ++r) {
                e0[r] = __builtin_amdgcn_exp2f(Sh[m][0][r]);
                e1[r] = __builtin_amdgcn_exp2f(Sh[m][1][r]);
            }
            unsigned A0 = cvt_pk_bf16(e0[0], e0[1]);
            unsigned A1 = cvt_pk_bf16(e0[2], e0[3]);
            unsigned B0 = cvt_pk_bf16(e1[0], e1[1]);
            unsigned B1 = cvt_pk_bf16(e1[2], e1[3]);
            asm("v_permlane32_swap_b32 %0, %1" : "+v"(A0), "+v"(B0));
            asm("v_permlane16_swap_b32 %0, %1" : "+v"(A0), "+v"(B0));
            asm("v_permlane32_swap_b32 %0, %1" : "+v"(A1), "+v"(B1));
            asm("v_permlane16_swap_b32 %0, %1" : "+v"(A1), "+v"(B1));
            uint4v pw = { A0, A1, B0, B1 };
            paD[m] = *(short8*)&pw;
            Ol[m] = __builtin_amdgcn_mfma_f32_16x16x32_bf16(paD[m], ones, Ol[m], 0, 0, 0);
        }
    };

    stageK(0, 0);      // issued FIRST: oldest 2 in the vmcnt FIFO
    stageV(0, 0);
    int cur = 0;
    for (int j0 = 0; j0 < LL; j0 += 64) {
        bool more = (j0 + 64 < LL);

        // ---- phase 1: K(t) ready (V(t) may still be in flight) ----
        asm volatile("s_waitcnt vmcnt(8)" ::: "memory");
        __builtin_amdgcn_s_barrier();
        if (more) { stageK(j0 + 64, cur ^ 1); stageV(j0 + 64, cur ^ 1); }

        const unsigned short* kbp = kt[cur];
        const unsigned short* vbp = vt[cur];

        floatx4 Sa[2][2], Sb[2][2];
#pragma unroll
        for (int m = 0; m < 2; ++m)
#pragma unroll
            for (int nt = 0; nt < 2; ++nt) { Sa[m][nt] = {0.f,0.f,0.f,0.f}; Sb[m][nt] = {0.f,0.f,0.f,0.f}; }

        // ---- S half0 (j 0..31) ----
        short8 ka0 = *(const short8*)(kbp + kro[0]);
        short8 ka1 = *(const short8*)(kbp + kro[1]);
        short8 kb0 = *(const short8*)(kbp + kro[0] + 1024);
        short8 kb1 = *(const short8*)(kbp + kro[1] + 1024);
#pragma unroll
        for (int m = 0; m < 2; ++m) {
            Sa[m][0] = __builtin_amdgcn_mfma_f32_16x16x32_bf16(ka0, qf[m][0], Sa[m][0], 0, 0, 0);
            Sa[m][0] = __builtin_amdgcn_mfma_f32_16x16x32_bf16(ka1, qf[m][1], Sa[m][0], 0, 0, 0);
            Sa[m][1] = __builtin_amdgcn_mfma_f32_16x16x32_bf16(kb0, qf[m][0], Sa[m][1], 0, 0, 0);
            Sa[m][1] = __builtin_amdgcn_mfma_f32_16x16x32_bf16(kb1, qf[m][1], Sa[m][1], 0, 0, 0);
        }
        // ---- S half1 (j 32..63) ----
        short8 kc0 = *(const short8*)(kbp + kro[0] + 2048);
        short8 kc1 = *(const short8*)(kbp + kro[1] + 2048);
        short8 kd0 = *(const short8*)(kbp + kro[0] + 3072);
        short8 kd1 = *(const short8*)(kbp + kro[1] + 3072);
#pragma unroll
        for (int m = 0; m < 2; ++m) {
            Sb[m][0] = __builtin_amdgcn_mfma_f32_16x16x32_bf16(kc0, qf[m][0], Sb[m][0], 0, 0, 0);
            Sb[m][0] = __builtin_amdgcn_mfma_f32_16x16x32_bf16(kc1, qf[m][1], Sb[m][0], 0, 0, 0);
            Sb[m][1] = __builtin_amdgcn_mfma_f32_16x16x32_bf16(kd0, qf[m][0], Sb[m][1], 0, 0, 0);
            Sb[m][1] = __builtin_amdgcn_mfma_f32_16x16x32_bf16(kd1, qf[m][1], Sb[m][1], 0, 0, 0);
        }

        short8 pa0[2], pa1[2];
        softmax_half(Sa, pa0);

        // ---- phase 2: V(t) ready; t+1's 10 DMAs remain in flight ----
        if (more) asm volatile("s_waitcnt vmcnt(10)" ::: "memory");
        else      asm volatile("s_waitcnt vmcnt(0)"  ::: "memory");
        __builtin_amdgcn_s_barrier();

        // ---- PV half0, first 8 c-tiles ----
        __builtin_amdgcn_s_setprio(1);
#pragma unroll
        for (int nt = 0; nt < 8; ++nt) {
            short8 vf = *(const short8*)(vbp + vro[0] + nt * 1024);
#pragma unroll
            for (int m = 0; m < 2; ++m)
                O[m][nt] = __builtin_amdgcn_mfma_f32_16x16x32_bf16(pa0[m], vf, O[m][nt], 0, 0, 0);
        }
        __builtin_amdgcn_s_setprio(0);

        softmax_half(Sb, pa1);     // overlaps PV-half0 tail / next PV issue

        __builtin_amdgcn_s_setprio(1);
#pragma unroll
        for (int nt = 8; nt < 16; ++nt) {
            short8 vf = *(const short8*)(vbp + vro[0] + nt * 1024);
#pragma unroll
            for (int m = 0; m < 2; ++m)
                O[m][nt] = __builtin_amdgcn_mfma_f32_16x16x32_bf16(pa0[m], vf, O[m][nt], 0, 0, 0);
        }
#pragma unroll
        for (int nt = 0; nt < 16; ++nt) {
            short8 vf = *(const short8*)(vbp + vro[1] + nt * 1024);
#pragma unroll
            for (int m = 0; m < 2; ++m)
                O[m][nt] = __builtin_amdgcn_mfma_f32_16x16x32_bf16(pa1[m], vf, O[m][nt], 0, 0, 0);
        }
        __builtin_amdgcn_s_setprio(0);
        cur ^= 1;
    }

    // ---- epilogue: out = gamma * O / l + x ----
    float linv[2][4];
#pragma unroll
    for (int m = 0; m < 2; ++m)
#pragma unroll
        for (int r = 0; r < 4; ++r) linv[m][r] = 1.f / Ol[m][r];

    float gam = gamma[0];
#pragma unroll
    for (int m = 0; m < 2; ++m)
#pragma unroll
        for (int nt = 0; nt < 16; ++nt) {
            int c = c0 + nt * 16 + lane16;
            size_t base = ((size_t)b * CC + c) * LL + iw + m * 16 + g * 4;
            floatx4 xv = *(const floatx4*)(x + base);
            floatx4 o;
#pragma unroll
            for (int r = 0; r < 4; ++r) o[r] = gam * (O[m][nt][r] * linv[m][r]) + xv[r];
            *(floatx4*)(out + base) = o;
        }
}

extern "C" void kernel_launch(void* const* d_in, const int* in_sizes, int n_in,
                              void* d_out, int out_size, void* d_ws, size_t ws_size,
                              hipStream_t stream) {
    const float* x     = (const float*)d_in[0];
    const float* Wq    = (const float*)d_in[1];
    const float* bq    = (const float*)d_in[2];
    const float* Wk    = (const float*)d_in[3];
    const float* bk    = (const float*)d_in[4];
    const float* Wv    = (const float*)d_in[5];
    const float* bv    = (const float*)d_in[6];
    const float* gamma = (const float*)d_in[7];
    float* out = (float*)d_out;

    unsigned short* xt  = (unsigned short*)d_ws;          // B*L*C      = 16,777,216
    unsigned short* qb  = xt  + (size_t)BB * LL * CC;     // B*L*64     =  2,097,152
    unsigned short* kb  = qb  + (size_t)BB * LL * DQK;
    unsigned short* vb  = kb  + (size_t)BB * LL * DQK;    // B*C*L      = 16,777,216
    unsigned short* wqb = vb  + (size_t)BB * CC * LL;     // 32768
    unsigned short* wkb = wqb + (size_t)DQK * CC;
    unsigned short* wvb = wkb + (size_t)DQK * CC;         // 262144

    k_transpose<<<dim3(LL / 64, CC / 64, BB), 256, 0, stream>>>(x, xt);
    k_castw<<<dim3((CC * CC) / 256), 256, 0, stream>>>(Wq, Wk, Wv, wqb, wkb, wvb);
    k_projall<<<dim3(LL / 64, BB), 256, 0, stream>>>(xt, wqb, wkb, wvb, bq, bk, bv, qb, kb, vb);
    k_attn<<<dim3(LL / 128, BB, CC / 256), 256, 0, stream>>>(qb, kb, vb, x, gamma, out);
}

// Round 4
// 339.655 us; speedup vs baseline: 1.0579x; 1.0579x over previous
//
#include <hip/hip_runtime.h>
#include <math.h>

#define BB 8
#define CC 512
#define LL 4096
#define DQK 64

typedef short short8 __attribute__((ext_vector_type(8)));
typedef unsigned short ushort4v __attribute__((ext_vector_type(4)));
typedef unsigned short ushort8v __attribute__((ext_vector_type(8)));
typedef float floatx4 __attribute__((ext_vector_type(4)));
typedef unsigned int uint4v __attribute__((ext_vector_type(4)));

__device__ __forceinline__ unsigned short f2bf(float f) {
    union { float f; unsigned u; } v; v.f = f;
    unsigned r = v.u + 0x7fffu + ((v.u >> 16) & 1u);
    return (unsigned short)(r >> 16);
}

// async global->LDS DMA, 16B per lane. LDS dest is wave-uniform base + lane*16.
__device__ __forceinline__ void load_lds16(const void* gptr, void* lptr) {
    __builtin_amdgcn_global_load_lds(
        (const __attribute__((address_space(1))) unsigned int*)gptr,
        (__attribute__((address_space(3))) unsigned int*)lptr, 16, 0, 0);
}

__device__ __forceinline__ unsigned cvt_pk_bf16(float lo, float hi) {
    unsigned r;
    asm("v_cvt_pk_bf16_f32 %0, %1, %2" : "=v"(r) : "v"(lo), "v"(hi));
    return r;
}

// ---------------- weight cast ----------------
__global__ void k_castw(const float* __restrict__ wq, const float* __restrict__ wk,
                        const float* __restrict__ wv,
                        unsigned short* __restrict__ wqb, unsigned short* __restrict__ wkb,
                        unsigned short* __restrict__ wvb) {
    int i = blockIdx.x * 256 + threadIdx.x;   // grid covers 262144
    if (i < DQK * CC) { wqb[i] = f2bf(wq[i]); wkb[i] = f2bf(wk[i]); }
    wvb[i] = f2bf(wv[i]);
}

// ---------------- fused transpose + cast + q/k/v projection ----------------
// Round-4: xt intermediate DELETED. Each block reads its 512c x 64l f32 slab of x
// COALESCED (natural [c][l] layout), converts to bf16 in-register, and scatter-
// writes into the swizzled LDS xtile[l][c] directly (scalar 2B writes; the
// bandwidth-critical READ side keeps the proven conflict-free b128 granule-XOR
// pattern). Saves 67 MB HBM (xt write+read), one launch, and the old transpose
// kernel's 8-way scalar-read LDS conflict.
// W prefetch: rolling 8-fragment wA/wB half-steps (round-3 pattern, 64 VGPR).
// z<8: V rows (out [d][l]);  z==8: Q (out [l][d], LOG2E folded);  z==9: K.
__global__ __launch_bounds__(256) void k_prep(const float* __restrict__ x,
                                              const unsigned short* __restrict__ wqb,
                                              const unsigned short* __restrict__ wkb,
                                              const unsigned short* __restrict__ wvb,
                                              const float* __restrict__ bq,
                                              const float* __restrict__ bk,
                                              const float* __restrict__ bv,
                                              unsigned short* __restrict__ qout,
                                              unsigned short* __restrict__ kout,
                                              unsigned short* __restrict__ vout) {
    int l0 = blockIdx.x * 64;
    int b  = blockIdx.y;
    int tid = threadIdx.x;
    int w = tid >> 6, lane = tid & 63;
    int lane16 = lane & 15, g = lane >> 4;
    __shared__ unsigned short xtile[64 * 512];

    // ---- stage: transpose + cast x[c][l] -> xtile[l][swizzled c] ----
    {
        int cr = tid >> 2;            // c within 64-row group
        int ch = (tid & 3) * 16;      // l chunk base
#pragma unroll
        for (int cc = 0; cc < 8; ++cc) {
            int c  = cc * 64 + cr;
            int gc = c >> 3;
            int cl = c & 7;
            const float* src = x + ((size_t)b * CC + c) * LL + l0 + ch;
#pragma unroll
            for (int j = 0; j < 4; ++j) {
                floatx4 v = *(const floatx4*)(src + j * 4);
#pragma unroll
                for (int e = 0; e < 4; ++e) {
                    int l  = ch + j * 4 + e;
                    int pg = (gc & 56) | ((gc ^ (l & 7)) & 7);   // granule XOR swizzle
                    xtile[l * 512 + pg * 8 + cl] = f2bf(v[e]);
                }
            }
        }
    }

    int xe = (g ^ (lane16 & 7)) * 8;
    int xo = ((g + 4) ^ (lane16 & 7)) * 8;

    // 8 W fragments for half-step hs = z*2 + kh (kk = kh*8 .. kh*8+7)
    auto loadW8 = [&](short8 (&af)[8], int hs) {
        int z = hs >> 1, kh = hs & 1;
        const unsigned short* base;
        if (z < 8)       base = wvb + (size_t)(z * 64 + w * 16 + lane16) * CC;
        else if (z == 8) base = wqb + (size_t)(w * 16 + lane16) * CC;
        else             base = wkb + (size_t)(w * 16 + lane16) * CC;
        base += g * 8 + kh * 256;          // kh*8 frags * 32 ushort stride
#pragma unroll
        for (int kk = 0; kk < 8; ++kk) af[kk] = *(const short8*)(base + kk * 32);
    };

    short8 wA[8], wB[8];
    loadW8(wA, 0);
    __syncthreads();   // xtile writes visible

    for (int z = 0; z < 10; ++z) {
        loadW8(wB, z * 2 + 1);                 // prefetch kh=1 under kh=0 MFMAs
        floatx4 acc[4];
#pragma unroll
        for (int nt = 0; nt < 4; ++nt) acc[nt] = {0.f, 0.f, 0.f, 0.f};
#pragma unroll
        for (int nt = 0; nt < 4; ++nt)
#pragma unroll
            for (int kk = 0; kk < 8; ++kk) {
                int off = (nt * 16 + lane16) * 512 + (kk >> 1) * 64 + ((kk & 1) ? xo : xe);
                short8 bfrag = *(const short8*)(xtile + off);
                acc[nt] = __builtin_amdgcn_mfma_f32_16x16x32_bf16(wA[kk], bfrag, acc[nt], 0, 0, 0);
            }
        if (z + 1 < 10) loadW8(wA, (z + 1) * 2);   // prefetch next z kh=0 under kh=1
#pragma unroll
        for (int nt = 0; nt < 4; ++nt)
#pragma unroll
            for (int kk = 0; kk < 8; ++kk) {
                int kk8 = kk + 8;
                int off = (nt * 16 + lane16) * 512 + (kk8 >> 1) * 64 + ((kk8 & 1) ? xo : xe);
                short8 bfrag = *(const short8*)(xtile + off);
                acc[nt] = __builtin_amdgcn_mfma_f32_16x16x32_bf16(wB[kk], bfrag, acc[nt], 0, 0, 0);
            }
        // write out z's results
#pragma unroll
        for (int nt = 0; nt < 4; ++nt) {
            int l = l0 + nt * 16 + lane16;
            if (z < 8) {
#pragma unroll
                for (int r = 0; r < 4; ++r) {
                    int d = z * 64 + w * 16 + g * 4 + r;
                    vout[((size_t)b * CC + d) * LL + l] = f2bf(acc[nt][r] + bv[d]);
                }
            } else {
                const float* bias = (z == 8) ? bq : bk;
                float sc = (z == 8) ? 1.4426950408889634f : 1.0f;
                ushort4v o;
#pragma unroll
                for (int r = 0; r < 4; ++r)
                    o[r] = f2bf((acc[nt][r] + bias[w * 16 + g * 4 + r]) * sc);
                unsigned short* dst = ((z == 8) ? qout : kout)
                                      + ((size_t)b * LL + l) * DQK + w * 16 + g * 4;
                *(ushort4v*)dst = o;
            }
        }
    }
}

// ---------------- fused flash attention (round-2 schedule, proven 180 us) ----------------
// grid: (L/128, B, C/256). 4 waves x 32 q-rows.
//  * swapped QK^T, in-register P repack (cvt_pk + permlane), ones-MFMA denominator
//  * j-tile split into two independent 32-j halves for MFMA/VALU overlap
//  * single __syncthreads-drained double-buffer (counted-vmcnt variant REGRESSED:
//    cross-block overlap at 2 blocks/CU already hides the drain; extra barrier hurt)
//  * XCD-aware remap: 32 blocks sharing one (b,z) K/V set -> same XCD L2
__global__ __launch_bounds__(256, 2) void k_attn(const unsigned short* __restrict__ q,
                                                 const unsigned short* __restrict__ kws,
                                                 const unsigned short* __restrict__ vws,
                                                 const float* __restrict__ x,
                                                 const float* __restrict__ gamma,
                                                 float* __restrict__ out) {
    // bijective remap: hw bid -> (bx, by, bz); group g=(b,z) of 32 blocks -> XCD g&7
    int bid = blockIdx.x + 32 * blockIdx.y + 256 * blockIdx.z;
    int x8  = bid & 7;
    int ii  = bid >> 3;                  // 0..63
    int wg  = (x8 + 8 * (ii >> 5)) * 32 + (ii & 31);
    int i0 = (wg & 31) * 128;
    int b  = (wg >> 5) & 7;
    int c0 = (wg >> 8) * 256;

    int tid = threadIdx.x;
    int w = tid >> 6, lane = tid & 63;
    int lane16 = lane & 15, g = lane >> 4;
    int iw = i0 + w * 32;

    __shared__ unsigned short kt[2][64 * 64];    // 2 x  8 KB: K tile [j][d], swizzled
    __shared__ unsigned short vt[2][256 * 64];   // 2 x 32 KB: V tile [c][j], swizzled

    // Q fragments (B-operand of swapped QK^T: col=lane16 -> q-row i)
    short8 qf[2][2];
#pragma unroll
    for (int m = 0; m < 2; ++m) {
        const unsigned short* qrow = q + ((size_t)b * LL + iw + m * 16 + lane16) * DQK + g * 8;
        qf[m][0] = *(const short8*)(qrow);
        qf[m][1] = *(const short8*)(qrow + 32);
    }

    const unsigned short* kglob = kws + (size_t)b * LL * DQK;
    const unsigned short* vglob = vws + ((size_t)b * CC + c0) * LL;
    int gr    = (tid & 7) ^ ((tid >> 3) & 7);
    int koff0 = (tid >> 3) * DQK + gr * 8;
    int voff0 = (tid >> 3) * LL  + gr * 8;

    // fragment read offsets (ushort units) within one buffer
    int kro[2], vro[2];
#pragma unroll
    for (int kk = 0; kk < 2; ++kk) {
        int sw = (kk * 4 + g) ^ (lane16 & 7);
        kro[kk] = lane16 * 64 + sw * 8;
        vro[kk] = lane16 * 64 + sw * 8;
    }

    short8 ones;
#pragma unroll
    for (int j = 0; j < 8; ++j) ones[j] = (short)0x3f80;   // bf16 1.0

    floatx4 O[2][16];
#pragma unroll
    for (int m = 0; m < 2; ++m)
#pragma unroll
        for (int nt = 0; nt < 16; ++nt) O[m][nt] = {0.f, 0.f, 0.f, 0.f};
    floatx4 Ol[2];
#pragma unroll
    for (int m = 0; m < 2; ++m) Ol[m] = {0.f, 0.f, 0.f, 0.f};

    auto stage = [&](int j0n, int buf) {
        const unsigned short* ks = kglob + j0n * DQK + koff0;
        unsigned short* kd = &kt[buf][tid * 8];
        load_lds16(ks,        kd);
        load_lds16(ks + 2048, kd + 2048);
        const unsigned short* vs = vglob + j0n + voff0;
        unsigned short* vd = &vt[buf][tid * 8];
#pragma unroll
        for (int i = 0; i < 8; ++i)
            load_lds16(vs + i * 131072, vd + i * 2048);
    };

    // exp + in-register repack + ones-MFMA for one 32-j half
    auto softmax_half = [&](floatx4 (&Sh)[2][2], short8 (&paD)[2]) {
#pragma unroll
        for (int m = 0; m < 2; ++m) {
            float e0[4], e1[4];
#pragma unroll
            for (int r = 0; r < 4; ++r) {
                e0[r] = __builtin_amdgcn_exp2f(Sh[m][0][r]);
                e1[r] = __builtin_amdgcn_exp2f(Sh[m][1][r]);
            }
            unsigned A0 = cvt_pk_bf16(e0[0], e0[1]);
            unsigned A1 = cvt_pk_bf16(e0[2], e0[3]);
            unsigned B0 = cvt_pk_bf16(e1[0], e1[1]);
            unsigned B1 = cvt_pk_bf16(e1[2], e1[3]);
            asm("v_permlane32_swap_b32 %0, %1" : "+v"(A0), "+v"(B0));
            asm("v_permlane16_swap_b32 %0, %1" : "+v"(A0), "+v"(B0));
            asm("v_permlane32_swap_b32 %0, %1" : "+v"(A1), "+v"(B1));
            asm("v_permlane16_swap_b32 %0, %1" : "+v"(A1), "+v"(B1));
            uint4v pw = { A0, A1, B0, B1 };
            paD[m] = *(short8*)&pw;
            Ol[m] = __builtin_amdgcn_mfma_f32_16x16x32_bf16(paD[m], ones, Ol[m], 0, 0, 0);
        }
    };

    stage(0, 0);
    int cur = 0;
    for (int j0 = 0; j0 < LL; j0 += 64) {
        __syncthreads();                      // buf[cur] DMA drained; prev reads of buf[cur^1] done
        if (j0 + 64 < LL) stage(j0 + 64, cur ^ 1);

        const unsigned short* kbp = kt[cur];
        const unsigned short* vbp = vt[cur];

        floatx4 Sa[2][2], Sb[2][2];
#pragma unroll
        for (int m = 0; m < 2; ++m)
#pragma unroll
            for (int nt = 0; nt < 2; ++nt) { Sa[m][nt] = {0.f,0.f,0.f,0.f}; Sb[m][nt] = {0.f,0.f,0.f,0.f}; }

        // ---- S half0 (j 0..31) ----
        short8 ka0 = *(const short8*)(kbp + kro[0]);
        short8 ka1 = *(const short8*)(kbp + kro[1]);
        short8 kb0 = *(const short8*)(kbp + kro[0] + 1024);
        short8 kb1 = *(const short8*)(kbp + kro[1] + 1024);
#pragma unroll
        for (int m = 0; m < 2; ++m) {
            Sa[m][0] = __builtin_amdgcn_mfma_f32_16x16x32_bf16(ka0, qf[m][0], Sa[m][0], 0, 0, 0);
            Sa[m][0] = __builtin_amdgcn_mfma_f32_16x16x32_bf16(ka1, qf[m][1], Sa[m][0], 0, 0, 0);
            Sa[m][1] = __builtin_amdgcn_mfma_f32_16x16x32_bf16(kb0, qf[m][0], Sa[m][1], 0, 0, 0);
            Sa[m][1] = __builtin_amdgcn_mfma_f32_16x16x32_bf16(kb1, qf[m][1], Sa[m][1], 0, 0, 0);
        }
        // ---- S half1 (j 32..63) ----
        short8 kc0 = *(const short8*)(kbp + kro[0] + 2048);
        short8 kc1 = *(const short8*)(kbp + kro[1] + 2048);
        short8 kd0 = *(const short8*)(kbp + kro[0] + 3072);
        short8 kd1 = *(const short8*)(kbp + kro[1] + 3072);
#pragma unroll
        for (int m = 0; m < 2; ++m) {
            Sb[m][0] = __builtin_amdgcn_mfma_f32_16x16x32_bf16(kc0, qf[m][0], Sb[m][0], 0, 0, 0);
            Sb[m][0] = __builtin_amdgcn_mfma_f32_16x16x32_bf16(kc1, qf[m][1], Sb[m][0], 0, 0, 0);
            Sb[m][1] = __builtin_amdgcn_mfma_f32_16x16x32_bf16(kd0, qf[m][0], Sb[m][1], 0, 0, 0);
            Sb[m][1] = __builtin_amdgcn_mfma_f32_16x16x32_bf16(kd1, qf[m][1], Sb[m][1], 0, 0, 0);
        }

        short8 pa0[2], pa1[2];
        softmax_half(Sa, pa0);     // independent of Sb MFMAs -> scheduler overlaps

        // ---- PV half0, first 8 c-tiles ----
        __builtin_amdgcn_s_setprio(1);
#pragma unroll
        for (int nt = 0; nt < 8; ++nt) {
            short8 vf = *(const short8*)(vbp + vro[0] + nt * 1024);
#pragma unroll
            for (int m = 0; m < 2; ++m)
                O[m][nt] = __builtin_amdgcn_mfma_f32_16x16x32_bf16(pa0[m], vf, O[m][nt], 0, 0, 0);
        }
        __builtin_amdgcn_s_setprio(0);

        softmax_half(Sb, pa1);     // overlaps PV-half0 tail / next PV issue

        __builtin_amdgcn_s_setprio(1);
#pragma unroll
        for (int nt = 8; nt < 16; ++nt) {
            short8 vf = *(const short8*)(vbp + vro[0] + nt * 1024);
#pragma unroll
            for (int m = 0; m < 2; ++m)
                O[m][nt] = __builtin_amdgcn_mfma_f32_16x16x32_bf16(pa0[m], vf, O[m][nt], 0, 0, 0);
        }
#pragma unroll
        for (int nt = 0; nt < 16; ++nt) {
            short8 vf = *(const short8*)(vbp + vro[1] + nt * 1024);
#pragma unroll
            for (int m = 0; m < 2; ++m)
                O[m][nt] = __builtin_amdgcn_mfma_f32_16x16x32_bf16(pa1[m], vf, O[m][nt], 0, 0, 0);
        }
        __builtin_amdgcn_s_setprio(0);
        cur ^= 1;
    }

    // ---- epilogue: out = gamma * O / l + x ----
    float linv[2][4];
#pragma unroll
    for (int m = 0; m < 2; ++m)
#pragma unroll
        for (int r = 0; r < 4; ++r) linv[m][r] = 1.f / Ol[m][r];

    float gam = gamma[0];
#pragma unroll
    for (int m = 0; m < 2; ++m)
#pragma unroll
        for (int nt = 0; nt < 16; ++nt) {
            int c = c0 + nt * 16 + lane16;
            size_t base = ((size_t)b * CC + c) * LL + iw + m * 16 + g * 4;
            floatx4 xv = *(const floatx4*)(x + base);
            floatx4 o;
#pragma unroll
            for (int r = 0; r < 4; ++r) o[r] = gam * (O[m][nt][r] * linv[m][r]) + xv[r];
            *(floatx4*)(out + base) = o;
        }
}

extern "C" void kernel_launch(void* const* d_in, const int* in_sizes, int n_in,
                              void* d_out, int out_size, void* d_ws, size_t ws_size,
                              hipStream_t stream) {
    const float* x     = (const float*)d_in[0];
    const float* Wq    = (const float*)d_in[1];
    const float* bq    = (const float*)d_in[2];
    const float* Wk    = (const float*)d_in[3];
    const float* bk    = (const float*)d_in[4];
    const float* Wv    = (const float*)d_in[5];
    const float* bv    = (const float*)d_in[6];
    const float* gamma = (const float*)d_in[7];
    float* out = (float*)d_out;

    unsigned short* qb  = (unsigned short*)d_ws;          // B*L*64     =  2,097,152
    unsigned short* kb  = qb  + (size_t)BB * LL * DQK;
    unsigned short* vb  = kb  + (size_t)BB * LL * DQK;    // B*C*L      = 16,777,216
    unsigned short* wqb = vb  + (size_t)BB * CC * LL;     // 32768
    unsigned short* wkb = wqb + (size_t)DQK * CC;
    unsigned short* wvb = wkb + (size_t)DQK * CC;         // 262144

    k_castw<<<dim3((CC * CC) / 256), 256, 0, stream>>>(Wq, Wk, Wv, wqb, wkb, wvb);
    k_prep<<<dim3(LL / 64, BB), 256, 0, stream>>>(x, wqb, wkb, wvb, bq, bk, bv, qb, kb, vb);
    k_attn<<<dim3(LL / 128, BB, CC / 256), 256, 0, stream>>>(qb, kb, vb, x, gamma, out);
}

// Round 5
// 329.030 us; speedup vs baseline: 1.0921x; 1.0323x over previous
//
#include <hip/hip_runtime.h>
#include <math.h>

#define BB 8
#define CC 512
#define LL 4096
#define DQK 64

typedef short short8 __attribute__((ext_vector_type(8)));
typedef unsigned short ushort4v __attribute__((ext_vector_type(4)));
typedef unsigned short ushort8v __attribute__((ext_vector_type(8)));
typedef float floatx4 __attribute__((ext_vector_type(4)));
typedef float floatx2 __attribute__((ext_vector_type(2)));
typedef unsigned int uint4v __attribute__((ext_vector_type(4)));

__device__ __forceinline__ unsigned short f2bf(float f) {
    union { float f; unsigned u; } v; v.f = f;
    unsigned r = v.u + 0x7fffu + ((v.u >> 16) & 1u);
    return (unsigned short)(r >> 16);
}

// async global->LDS DMA, 16B per lane. LDS dest is wave-uniform base + lane*16.
__device__ __forceinline__ void load_lds16(const void* gptr, void* lptr) {
    __builtin_amdgcn_global_load_lds(
        (const __attribute__((address_space(1))) unsigned int*)gptr,
        (__attribute__((address_space(3))) unsigned int*)lptr, 16, 0, 0);
}

__device__ __forceinline__ unsigned cvt_pk_bf16(float lo, float hi) {
    unsigned r;
    asm("v_cvt_pk_bf16_f32 %0, %1, %2" : "=v"(r) : "v"(lo), "v"(hi));
    return r;
}

// ---------------- weight cast ----------------
__global__ void k_castw(const float* __restrict__ wq, const float* __restrict__ wk,
                        const float* __restrict__ wv,
                        unsigned short* __restrict__ wqb, unsigned short* __restrict__ wkb,
                        unsigned short* __restrict__ wvb) {
    int i = blockIdx.x * 256 + threadIdx.x;   // grid covers 262144
    if (i < DQK * CC) { wqb[i] = f2bf(wq[i]); wkb[i] = f2bf(wk[i]); }
    wvb[i] = f2bf(wv[i]);
}

// ---------------- fused transpose + cast + q/k/v projection ----------------
// Round-5: both scalar paths removed.
//  * stage: granule-gather. Thread owns (64-c block, l-pair): 64 coalesced dwordx2
//    loads, cvt_pk_bf16 packing, 16 conflict-free ds_write_b128 (pg&7 spans all 8
//    bank-quads via lane>>5 and 2*(lane&3)+e). Replaces 128 8-way-conflicted scalar
//    u16 LDS writes + ~380 VALU of f2bf.
//  * V path (z<8): SWAPPED mfma operands (frag loads identical, arg order flipped)
//    -> D row = g*4+r = l (consecutive!), col = lane16 = d. Acc goes through a
//    wave-private LDS tile (no barrier, lgkmcnt only) and stores as coalesced
//    dwordx4 (64B segments). Replaces 128 scalar scattered global stores/thread.
//  * q/k (z=8,9): original order/stores.
__global__ __launch_bounds__(256) void k_prep(const float* __restrict__ x,
                                              const unsigned short* __restrict__ wqb,
                                              const unsigned short* __restrict__ wkb,
                                              const unsigned short* __restrict__ wvb,
                                              const float* __restrict__ bq,
                                              const float* __restrict__ bk,
                                              const float* __restrict__ bv,
                                              unsigned short* __restrict__ qout,
                                              unsigned short* __restrict__ kout,
                                              unsigned short* __restrict__ vout) {
    int l0 = blockIdx.x * 64;
    int b  = blockIdx.y;
    int tid = threadIdx.x;
    int w = tid >> 6, lane = tid & 63;
    int lane16 = lane & 15, g = lane >> 4;
    __shared__ unsigned short xtile[64 * 512];
    __shared__ unsigned short wstage[4][16 * 72];   // per-wave V staging, 9 KB

    // ---- stage: x[c][l] -> xtile[l][swizzled c granules] ----
    {
        int cset = w * 2 + (lane >> 5);      // 0..7: which 64-c block
        int lp   = lane & 31;                // l-pair base = 2*lp
        const float* xb = x + ((size_t)b * CC + cset * 64) * LL + l0 + 2 * lp;

        floatx2 ld0[8], ld1[8];
        auto ldg = [&](floatx2* dst, int gj) {
#pragma unroll
            for (int k = 0; k < 8; ++k)
                dst[k] = *(const floatx2*)(xb + (size_t)(gj * 8 + k) * LL);
        };
        auto wr = [&](floatx2* src, int gj) {
            int cg = cset * 8 + gj;
#pragma unroll
            for (int e = 0; e < 2; ++e) {
                int l  = 2 * lp + e;
                int pg = (cg & 56) | ((cg ^ (l & 7)) & 7);
                uint4v u = { cvt_pk_bf16(src[0][e], src[1][e]),
                             cvt_pk_bf16(src[2][e], src[3][e]),
                             cvt_pk_bf16(src[4][e], src[5][e]),
                             cvt_pk_bf16(src[6][e], src[7][e]) };
                *(uint4v*)(xtile + l * 512 + pg * 8) = u;
            }
        };
        ldg(ld0, 0);
        ldg(ld1, 1);
#pragma unroll
        for (int gj = 0; gj < 8; ++gj) {
            floatx2* cur = (gj & 1) ? ld1 : ld0;
            wr(cur, gj);
            if (gj + 2 < 8) ldg(cur, gj + 2);
        }
    }

    int xe = (g ^ (lane16 & 7)) * 8;
    int xo = ((g + 4) ^ (lane16 & 7)) * 8;

    // 8 W fragments for half-step hs = z*2 + kh (kk = kh*8 .. kh*8+7)
    auto loadW8 = [&](short8 (&af)[8], int hs) {
        int z = hs >> 1, kh = hs & 1;
        const unsigned short* base;
        if (z < 8)       base = wvb + (size_t)(z * 64 + w * 16 + lane16) * CC;
        else if (z == 8) base = wqb + (size_t)(w * 16 + lane16) * CC;
        else             base = wkb + (size_t)(w * 16 + lane16) * CC;
        base += g * 8 + kh * 256;          // kh*8 frags * 32 ushort stride
#pragma unroll
        for (int kk = 0; kk < 8; ++kk) af[kk] = *(const short8*)(base + kk * 32);
    };

    short8 wA[8], wB[8];
    loadW8(wA, 0);
    __syncthreads();   // xtile writes visible

    // ---- V: z = 0..7, swapped operands ----
    unsigned short* ws = &wstage[w][0];
    for (int z = 0; z < 8; ++z) {
        loadW8(wB, z * 2 + 1);
        floatx4 acc[4];
#pragma unroll
        for (int nt = 0; nt < 4; ++nt) acc[nt] = {0.f, 0.f, 0.f, 0.f};
#pragma unroll
        for (int nt = 0; nt < 4; ++nt)
#pragma unroll
            for (int kk = 0; kk < 8; ++kk) {
                int off = (nt * 16 + lane16) * 512 + (kk >> 1) * 64 + ((kk & 1) ? xo : xe);
                short8 bfrag = *(const short8*)(xtile + off);
                acc[nt] = __builtin_amdgcn_mfma_f32_16x16x32_bf16(bfrag, wA[kk], acc[nt], 0, 0, 0);
            }
        loadW8(wA, (z + 1) * 2);
#pragma unroll
        for (int nt = 0; nt < 4; ++nt)
#pragma unroll
            for (int kk = 0; kk < 8; ++kk) {
                int kk8 = kk + 8;
                int off = (nt * 16 + lane16) * 512 + (kk8 >> 1) * 64 + ((kk8 & 1) ? xo : xe);
                short8 bfrag = *(const short8*)(xtile + off);
                acc[nt] = __builtin_amdgcn_mfma_f32_16x16x32_bf16(bfrag, wB[kk], acc[nt], 0, 0, 0);
            }
        // D: row (g*4+r) = l-sub, col (lane16) = d-sub. Stage into wave-private LDS.
        float bd = bv[z * 64 + w * 16 + lane16];
#pragma unroll
        for (int nt = 0; nt < 4; ++nt) {
            ushort4v o = { f2bf(acc[nt][0] + bd), f2bf(acc[nt][1] + bd),
                           f2bf(acc[nt][2] + bd), f2bf(acc[nt][3] + bd) };
            *(ushort4v*)(ws + lane16 * 72 + nt * 16 + g * 4) = o;
        }
        asm volatile("s_waitcnt lgkmcnt(0)" ::: "memory");
        __builtin_amdgcn_sched_barrier(0);
        // wave-coalesced readout: 16 d-rows x 128B -> dwordx4 stores, 64B segments
        int dr = lane >> 2, lc = lane & 3;
        ushort8v r0 = *(const ushort8v*)(ws + dr * 72 + lc * 16);
        ushort8v r1 = *(const ushort8v*)(ws + dr * 72 + lc * 16 + 8);
        size_t vbase = ((size_t)b * CC + z * 64 + w * 16 + dr) * LL + l0 + lc * 16;
        *(ushort8v*)(vout + vbase)     = r0;
        *(ushort8v*)(vout + vbase + 8) = r1;
        asm volatile("s_waitcnt lgkmcnt(0)" ::: "memory");   // reads done before next-z overwrite
        __builtin_amdgcn_sched_barrier(0);
    }

    // ---- Q/K: z = 8..9, original operand order ----
    for (int z = 8; z < 10; ++z) {
        loadW8(wB, z * 2 + 1);
        floatx4 acc[4];
#pragma unroll
        for (int nt = 0; nt < 4; ++nt) acc[nt] = {0.f, 0.f, 0.f, 0.f};
#pragma unroll
        for (int nt = 0; nt < 4; ++nt)
#pragma unroll
            for (int kk = 0; kk < 8; ++kk) {
                int off = (nt * 16 + lane16) * 512 + (kk >> 1) * 64 + ((kk & 1) ? xo : xe);
                short8 bfrag = *(const short8*)(xtile + off);
                acc[nt] = __builtin_amdgcn_mfma_f32_16x16x32_bf16(wA[kk], bfrag, acc[nt], 0, 0, 0);
            }
        if (z + 1 < 10) loadW8(wA, (z + 1) * 2);
#pragma unroll
        for (int nt = 0; nt < 4; ++nt)
#pragma unroll
            for (int kk = 0; kk < 8; ++kk) {
                int kk8 = kk + 8;
                int off = (nt * 16 + lane16) * 512 + (kk8 >> 1) * 64 + ((kk8 & 1) ? xo : xe);
                short8 bfrag = *(const short8*)(xtile + off);
                acc[nt] = __builtin_amdgcn_mfma_f32_16x16x32_bf16(wB[kk], bfrag, acc[nt], 0, 0, 0);
            }
        const float* bias = (z == 8) ? bq : bk;
        float sc = (z == 8) ? 1.4426950408889634f : 1.0f;
#pragma unroll
        for (int nt = 0; nt < 4; ++nt) {
            int l = l0 + nt * 16 + lane16;
            ushort4v o;
#pragma unroll
            for (int r = 0; r < 4; ++r)
                o[r] = f2bf((acc[nt][r] + bias[w * 16 + g * 4 + r]) * sc);
            unsigned short* dst = ((z == 8) ? qout : kout)
                                  + ((size_t)b * LL + l) * DQK + w * 16 + g * 4;
            *(ushort4v*)dst = o;
        }
    }
}

// ---------------- fused flash attention (round-2 schedule, proven 181 us) ----------------
// grid: (L/128, B, C/256). 4 waves x 32 q-rows.
//  * swapped QK^T, in-register P repack (cvt_pk + permlane), ones-MFMA denominator
//  * j-tile split into two independent 32-j halves for MFMA/VALU overlap
//  * single __syncthreads-drained double-buffer (counted-vmcnt variant REGRESSED:
//    cross-block overlap at 2 blocks/CU already hides the drain; extra barrier hurt)
//  * XCD-aware remap: 32 blocks sharing one (b,z) K/V set -> same XCD L2
__global__ __launch_bounds__(256, 2) void k_attn(const unsigned short* __restrict__ q,
                                                 const unsigned short* __restrict__ kws,
                                                 const unsigned short* __restrict__ vws,
                                                 const float* __restrict__ x,
                                                 const float* __restrict__ gamma,
                                                 float* __restrict__ out) {
    // bijective remap: hw bid -> (bx, by, bz); group g=(b,z) of 32 blocks -> XCD g&7
    int bid = blockIdx.x + 32 * blockIdx.y + 256 * blockIdx.z;
    int x8  = bid & 7;
    int ii  = bid >> 3;                  // 0..63
    int wg  = (x8 + 8 * (ii >> 5)) * 32 + (ii & 31);
    int i0 = (wg & 31) * 128;
    int b  = (wg >> 5) & 7;
    int c0 = (wg >> 8) * 256;

    int tid = threadIdx.x;
    int w = tid >> 6, lane = tid & 63;
    int lane16 = lane & 15, g = lane >> 4;
    int iw = i0 + w * 32;

    __shared__ unsigned short kt[2][64 * 64];    // 2 x  8 KB: K tile [j][d], swizzled
    __shared__ unsigned short vt[2][256 * 64];   // 2 x 32 KB: V tile [c][j], swizzled

    // Q fragments (B-operand of swapped QK^T: col=lane16 -> q-row i)
    short8 qf[2][2];
#pragma unroll
    for (int m = 0; m < 2; ++m) {
        const unsigned short* qrow = q + ((size_t)b * LL + iw + m * 16 + lane16) * DQK + g * 8;
        qf[m][0] = *(const short8*)(qrow);
        qf[m][1] = *(const short8*)(qrow + 32);
    }

    const unsigned short* kglob = kws + (size_t)b * LL * DQK;
    const unsigned short* vglob = vws + ((size_t)b * CC + c0) * LL;
    int gr    = (tid & 7) ^ ((tid >> 3) & 7);
    int koff0 = (tid >> 3) * DQK + gr * 8;
    int voff0 = (tid >> 3) * LL  + gr * 8;

    // fragment read offsets (ushort units) within one buffer
    int kro[2], vro[2];
#pragma unroll
    for (int kk = 0; kk < 2; ++kk) {
        int sw = (kk * 4 + g) ^ (lane16 & 7);
        kro[kk] = lane16 * 64 + sw * 8;
        vro[kk] = lane16 * 64 + sw * 8;
    }

    short8 ones;
#pragma unroll
    for (int j = 0; j < 8; ++j) ones[j] = (short)0x3f80;   // bf16 1.0

    floatx4 O[2][16];
#pragma unroll
    for (int m = 0; m < 2; ++m)
#pragma unroll
        for (int nt = 0; nt < 16; ++nt) O[m][nt] = {0.f, 0.f, 0.f, 0.f};
    floatx4 Ol[2];
#pragma unroll
    for (int m = 0; m < 2; ++m) Ol[m] = {0.f, 0.f, 0.f, 0.f};

    auto stage = [&](int j0n, int buf) {
        const unsigned short* ks = kglob + j0n * DQK + koff0;
        unsigned short* kd = &kt[buf][tid * 8];
        load_lds16(ks,        kd);
        load_lds16(ks + 2048, kd + 2048);
        const unsigned short* vs = vglob + j0n + voff0;
        unsigned short* vd = &vt[buf][tid * 8];
#pragma unroll
        for (int i = 0; i < 8; ++i)
            load_lds16(vs + i * 131072, vd + i * 2048);
    };

    // exp + in-register repack + ones-MFMA for one 32-j half
    auto softmax_half = [&](floatx4 (&Sh)[2][2], short8 (&paD)[2]) {
#pragma unroll
        for (int m = 0; m < 2; ++m) {
            float e0[4], e1[4];
#pragma unroll
            for (int r = 0; r < 4; ++r) {
                e0[r] = __builtin_amdgcn_exp2f(Sh[m][0][r]);
                e1[r] = __builtin_amdgcn_exp2f(Sh[m][1][r]);
            }
            unsigned A0 = cvt_pk_bf16(e0[0], e0[1]);
            unsigned A1 = cvt_pk_bf16(e0[2], e0[3]);
            unsigned B0 = cvt_pk_bf16(e1[0], e1[1]);
            unsigned B1 = cvt_pk_bf16(e1[2], e1[3]);
            asm("v_permlane32_swap_b32 %0, %1" : "+v"(A0), "+v"(B0));
            asm("v_permlane16_swap_b32 %0, %1" : "+v"(A0), "+v"(B0));
            asm("v_permlane32_swap_b32 %0, %1" : "+v"(A1), "+v"(B1));
            asm("v_permlane16_swap_b32 %0, %1" : "+v"(A1), "+v"(B1));
            uint4v pw = { A0, A1, B0, B1 };
            paD[m] = *(short8*)&pw;
            Ol[m] = __builtin_amdgcn_mfma_f32_16x16x32_bf16(paD[m], ones, Ol[m], 0, 0, 0);
        }
    };

    stage(0, 0);
    int cur = 0;
    for (int j0 = 0; j0 < LL; j0 += 64) {
        __syncthreads();                      // buf[cur] DMA drained; prev reads of buf[cur^1] done
        if (j0 + 64 < LL) stage(j0 + 64, cur ^ 1);

        const unsigned short* kbp = kt[cur];
        const unsigned short* vbp = vt[cur];

        floatx4 Sa[2][2], Sb[2][2];
#pragma unroll
        for (int m = 0; m < 2; ++m)
#pragma unroll
            for (int nt = 0; nt < 2; ++nt) { Sa[m][nt] = {0.f,0.f,0.f,0.f}; Sb[m][nt] = {0.f,0.f,0.f,0.f}; }

        // ---- S half0 (j 0..31) ----
        short8 ka0 = *(const short8*)(kbp + kro[0]);
        short8 ka1 = *(const short8*)(kbp + kro[1]);
        short8 kb0 = *(const short8*)(kbp + kro[0] + 1024);
        short8 kb1 = *(const short8*)(kbp + kro[1] + 1024);
#pragma unroll
        for (int m = 0; m < 2; ++m) {
            Sa[m][0] = __builtin_amdgcn_mfma_f32_16x16x32_bf16(ka0, qf[m][0], Sa[m][0], 0, 0, 0);
            Sa[m][0] = __builtin_amdgcn_mfma_f32_16x16x32_bf16(ka1, qf[m][1], Sa[m][0], 0, 0, 0);
            Sa[m][1] = __builtin_amdgcn_mfma_f32_16x16x32_bf16(kb0, qf[m][0], Sa[m][1], 0, 0, 0);
            Sa[m][1] = __builtin_amdgcn_mfma_f32_16x16x32_bf16(kb1, qf[m][1], Sa[m][1], 0, 0, 0);
        }
        // ---- S half1 (j 32..63) ----
        short8 kc0 = *(const short8*)(kbp + kro[0] + 2048);
        short8 kc1 = *(const short8*)(kbp + kro[1] + 2048);
        short8 kd0 = *(const short8*)(kbp + kro[0] + 3072);
        short8 kd1 = *(const short8*)(kbp + kro[1] + 3072);
#pragma unroll
        for (int m = 0; m < 2; ++m) {
            Sb[m][0] = __builtin_amdgcn_mfma_f32_16x16x32_bf16(kc0, qf[m][0], Sb[m][0], 0, 0, 0);
            Sb[m][0] = __builtin_amdgcn_mfma_f32_16x16x32_bf16(kc1, qf[m][1], Sb[m][0], 0, 0, 0);
            Sb[m][1] = __builtin_amdgcn_mfma_f32_16x16x32_bf16(kd0, qf[m][0], Sb[m][1], 0, 0, 0);
            Sb[m][1] = __builtin_amdgcn_mfma_f32_16x16x32_bf16(kd1, qf[m][1], Sb[m][1], 0, 0, 0);
        }

        short8 pa0[2], pa1[2];
        softmax_half(Sa, pa0);     // independent of Sb MFMAs -> scheduler overlaps

        // ---- PV half0, first 8 c-tiles ----
        __builtin_amdgcn_s_setprio(1);
#pragma unroll
        for (int nt = 0; nt < 8; ++nt) {
            short8 vf = *(const short8*)(vbp + vro[0] + nt * 1024);
#pragma unroll
            for (int m = 0; m < 2; ++m)
                O[m][nt] = __builtin_amdgcn_mfma_f32_16x16x32_bf16(pa0[m], vf, O[m][nt], 0, 0, 0);
        }
        __builtin_amdgcn_s_setprio(0);

        softmax_half(Sb, pa1);     // overlaps PV-half0 tail / next PV issue

        __builtin_amdgcn_s_setprio(1);
#pragma unroll
        for (int nt = 8; nt < 16; ++nt) {
            short8 vf = *(const short8*)(vbp + vro[0] + nt * 1024);
#pragma unroll
            for (int m = 0; m < 2; ++m)
                O[m][nt] = __builtin_amdgcn_mfma_f32_16x16x32_bf16(pa0[m], vf, O[m][nt], 0, 0, 0);
        }
#pragma unroll
        for (int nt = 0; nt < 16; ++nt) {
            short8 vf = *(const short8*)(vbp + vro[1] + nt * 1024);
#pragma unroll
            for (int m = 0; m < 2; ++m)
                O[m][nt] = __builtin_amdgcn_mfma_f32_16x16x32_bf16(pa1[m], vf, O[m][nt], 0, 0, 0);
        }
        __builtin_amdgcn_s_setprio(0);
        cur ^= 1;
    }

    // ---- epilogue: out = gamma * O / l + x ----
    float linv[2][4];
#pragma unroll
    for (int m = 0; m < 2; ++m)
#pragma unroll
        for (int r = 0; r < 4; ++r) linv[m][r] = 1.f / Ol[m][r];

    float gam = gamma[0];
#pragma unroll
    for (int m = 0; m < 2; ++m)
#pragma unroll
        for (int nt = 0; nt < 16; ++nt) {
            int c = c0 + nt * 16 + lane16;
            size_t base = ((size_t)b * CC + c) * LL + iw + m * 16 + g * 4;
            floatx4 xv = *(const floatx4*)(x + base);
            floatx4 o;
#pragma unroll
            for (int r = 0; r < 4; ++r) o[r] = gam * (O[m][nt][r] * linv[m][r]) + xv[r];
            *(floatx4*)(out + base) = o;
        }
}

extern "C" void kernel_launch(void* const* d_in, const int* in_sizes, int n_in,
                              void* d_out, int out_size, void* d_ws, size_t ws_size,
                              hipStream_t stream) {
    const float* x     = (const float*)d_in[0];
    const float* Wq    = (const float*)d_in[1];
    const float* bq    = (const float*)d_in[2];
    const float* Wk    = (const float*)d_in[3];
    const float* bk    = (const float*)d_in[4];
    const float* Wv    = (const float*)d_in[5];
    const float* bv    = (const float*)d_in[6];
    const float* gamma = (const float*)d_in[7];
    float* out = (float*)d_out;

    unsigned short* qb  = (unsigned short*)d_ws;          // B*L*64     =  2,097,152
    unsigned short* kb  = qb  + (size_t)BB * LL * DQK;
    unsigned short* vb  = kb  + (size_t)BB * LL * DQK;    // B*C*L      = 16,777,216
    unsigned short* wqb = vb  + (size_t)BB * CC * LL;     // 32768
    unsigned short* wkb = wqb + (size_t)DQK * CC;
    unsigned short* wvb = wkb + (size_t)DQK * CC;         // 262144

    k_castw<<<dim3((CC * CC) / 256), 256, 0, stream>>>(Wq, Wk, Wv, wqb, wkb, wvb);
    k_prep<<<dim3(LL / 64, BB), 256, 0, stream>>>(x, wqb, wkb, wvb, bq, bk, bv, qb, kb, vb);
    k_attn<<<dim3(LL / 128, BB, CC / 256), 256, 0, stream>>>(qb, kb, vb, x, gamma, out);
}